// Round 11
// baseline (188.513 us; speedup 1.0000x reference)
//
#include <hip/hip_runtime.h>

// out[b, 2n+o] = x[b,2n]*W[n,0,o] + x[b,2n+1]*W[n,1,o]
// W[n,m,o] = softmax_m(c[n,:,o]) = sigmoid(c[n,m,o] - c[n,1-m,o])
// Pure streaming: x read once (512 MiB), out written once (512 MiB), fp32.
//
// R10 (direction-batched phases, 4 rows/phase, 2 blocks/CU) = 187.1us / 5.74 TB/s.
// Confirmed mechanism: HBM DQ turnaround — aligned same-direction bursts win.
// This round: 2x longer runs (8 rows/phase = 128B/lane) + ONE block per CU
// (lb(1024,4) -> 128 VGPR, 16 waves/CU, all waves in one barrier group) so the
// whole CU switches direction in lockstep.
#define NCHUNK4   2048    // f32x4 per row
#define ROWS_PT   128     // rows per thread
#define PH        8       // rows per phase

typedef float f32x4 __attribute__((ext_vector_type(4)));

#define NTL(p)     __builtin_nontemporal_load(p)
#define NTS(p, v)  __builtin_nontemporal_store((v), (p))
// raw barrier: compiler fence + s_barrier, NO vmcnt drain
#define PHASE_BAR() do { asm volatile("" ::: "memory"); \
                         __builtin_amdgcn_s_barrier();  \
                         asm volatile("" ::: "memory"); } while (0)

__global__ __launch_bounds__(1024, 4)
void EfficientLearnableInterconnect_33913061769291_kernel(
        const float* __restrict__ x,
        const float* __restrict__ c,
        float* __restrict__ out) {
    const int tq    = threadIdx.x >> 8;           // quarter 0..3
    const int t     = threadIdx.x & 255;
    const int vblk  = blockIdx.x * 4 + tq;        // 0..1023
    const int strip = vblk & 7;
    const int rowg  = vblk >> 3;                  // 0..127
    const int chunk = strip * 256 + t;            // 0..2047
    const int row0  = rowg * ROWS_PT;

    // c[n] as f32x4: (c[n,0,0], c[n,0,1], c[n,1,0], c[n,1,1])
    const f32x4 c0 = ((const f32x4*)c)[2 * chunk];
    const f32x4 c1 = ((const f32x4*)c)[2 * chunk + 1];

    const float w000 = 1.f / (1.f + __expf(c0.z - c0.x));
    const float w010 = 1.f / (1.f + __expf(c0.x - c0.z));
    const float w001 = 1.f / (1.f + __expf(c0.w - c0.y));
    const float w011 = 1.f / (1.f + __expf(c0.y - c0.w));
    const float w100 = 1.f / (1.f + __expf(c1.z - c1.x));
    const float w110 = 1.f / (1.f + __expf(c1.x - c1.z));
    const float w101 = 1.f / (1.f + __expf(c1.w - c1.y));
    const float w111 = 1.f / (1.f + __expf(c1.y - c1.w));

#define APPLY(v) ({ f32x4 _o; \
    _o.x = (v).x * w000 + (v).y * w010; \
    _o.y = (v).x * w001 + (v).y * w011; \
    _o.z = (v).z * w100 + (v).w * w110; \
    _o.w = (v).z * w101 + (v).w * w111; _o; })

    const f32x4* __restrict__ xp = (const f32x4*)x + (size_t)row0 * NCHUNK4 + chunk;
    f32x4* __restrict__       op = (f32x4*)out     + (size_t)row0 * NCHUNK4 + chunk;

    f32x4 va[PH], vb[PH];

    // prologue: rows 0..7
    #pragma unroll
    for (int j = 0; j < PH; ++j)
        va[j] = NTL(xp + (size_t)j * NCHUNK4);

    for (int g = 0; g < 7; ++g) {
        // LOAD phase: rows +8..15
        #pragma unroll
        for (int j = 0; j < PH; ++j)
            vb[j] = NTL(xp + (size_t)(PH + j) * NCHUNK4);
        PHASE_BAR();
        // STORE phase: rows +0..7
        #pragma unroll
        for (int j = 0; j < PH; ++j)
            NTS(op + (size_t)j * NCHUNK4, APPLY(va[j]));
        // LOAD phase: rows +16..23
        #pragma unroll
        for (int j = 0; j < PH; ++j)
            va[j] = NTL(xp + (size_t)(2 * PH + j) * NCHUNK4);
        PHASE_BAR();
        // STORE phase: rows +8..15
        #pragma unroll
        for (int j = 0; j < PH; ++j)
            NTS(op + (size_t)(PH + j) * NCHUNK4, APPLY(vb[j]));
        xp += (size_t)2 * PH * NCHUNK4;
        op += (size_t)2 * PH * NCHUNK4;
    }
    // epilogue: rows 112..127 (xp/op at row 112)
    #pragma unroll
    for (int j = 0; j < PH; ++j)
        vb[j] = NTL(xp + (size_t)(PH + j) * NCHUNK4);
    PHASE_BAR();
    #pragma unroll
    for (int j = 0; j < PH; ++j)
        NTS(op + (size_t)j * NCHUNK4, APPLY(va[j]));
    #pragma unroll
    for (int j = 0; j < PH; ++j)
        NTS(op + (size_t)(PH + j) * NCHUNK4, APPLY(vb[j]));
#undef APPLY
}

extern "C" void kernel_launch(void* const* d_in, const int* in_sizes, int n_in,
                              void* d_out, int out_size, void* d_ws, size_t ws_size,
                              hipStream_t stream) {
    const float* x = (const float*)d_in[0];
    const float* c = (const float*)d_in[1];
    float* out = (float*)d_out;

    const dim3 grid(256);     // one 1024-thread block per CU; 1024 virtual quarters
    const dim3 block(1024);
    EfficientLearnableInterconnect_33913061769291_kernel<<<grid, block, 0, stream>>>(x, c, out);
}